// Round 2
// baseline (82.936 us; speedup 1.0000x reference)
//
#include <hip/hip_runtime.h>
#include <hip/hip_bf16.h>

// Problem constants (from reference): B=16, M=N=64, P=Q=3, OUT_U=OUT_V=256.
// Key reference facts:
//  - V is built from knot_u (source bug, kept faithful), u==v linspace, P==Q
//    => v-direction spans & basis are IDENTICAL to u-direction.
//  - Output takes only dims 0..2 of the 4-component ctrl points (no division).
//  - All inputs/outputs are float32 per setup_inputs()/reference dtype.
constexpr int B_   = 16;
constexpr int M_   = 64;
constexpr int N_   = 64;
constexpr int DEG  = 3;
constexpr int T_   = 256;   // OUT_U == OUT_V
constexpr int KLEN = 68;    // M + P + 1

__global__ __launch_bounds__(256)
void surf_eval_kernel(const float* __restrict__ ctrl,
                      const float* __restrict__ knot_u,
                      float* __restrict__ out) {
    const int b   = blockIdx.x >> 8;   // batch
    const int u   = blockIdx.x & 255;  // u-sample index for this block
    const int tid = threadIdx.x;       // v-sample index

    __shared__ float su[KLEN];         // normalized knots (U == V)
    __shared__ float sN[T_][4];        // basis per parameter sample
    __shared__ int   sspan[T_];
    __shared__ float rows[4][N_][4];   // 4 staged ctrl rows

    // --- normalized cumsum of knot_u[b] (np.cumsum is sequential; mirror it)
    if (tid == 0) {
        float acc = 0.f;
        for (int i = 0; i < KLEN; ++i) {
            acc += knot_u[b * KLEN + i];
            su[i] = acc;               // raw cumsum
        }
        const float c0 = su[0];
        const float d  = su[KLEN - 1] - c0;
        for (int i = 0; i < KLEN; ++i) su[i] = (su[i] - c0) / d;
    }
    __syncthreads();

    // --- per-thread parameter t (linspace(1e-5, 1-1e-5, 256))
    const float tt = 1e-5f + (float)tid * ((1.0f - 2e-5f) / 255.0f);

    // --- span: first-occurrence argmin of (t - U[s+3]) where > 1e-8 else 1.0
    float best = 1e30f; int bs = 0;
    for (int s = 0; s < KLEN - 2 * DEG; ++s) {       // 62 candidates
        float dd   = tt - su[s + DEG];
        float cand = (dd > 1e-8f) ? dd : 1.0f;
        if (cand < best) { best = cand; bs = s; }    // strict < keeps first min
    }
    const int span = bs + DEG;

    // --- Cox-de Boor, degree 3, exact reference arithmetic order
    float Ni[4] = {1.f, 0.f, 0.f, 0.f};
    for (int k = 1; k <= DEG; ++k) {
        float saved = 0.f;
        for (int r = 0; r < k; ++r) {
            const float K1   = su[span + r + 1];
            const float K2   = su[span + 1 - k + r];
            const float temp = Ni[r] / ((K1 - tt) + (tt - K2));
            Ni[r] = saved + (K1 - tt) * temp;
            saved = (tt - K2) * temp;
        }
        Ni[k] = saved;
    }
    sN[tid][0] = Ni[0]; sN[tid][1] = Ni[1];
    sN[tid][2] = Ni[2]; sN[tid][3] = Ni[3];
    sspan[tid] = span;
    __syncthreads();

    // --- u-direction values: identical parameter grid => read thread u's result
    const int   us  = sspan[u];
    const float Nu0 = sN[u][0], Nu1 = sN[u][1], Nu2 = sN[u][2], Nu3 = sN[u][3];

    // --- stage ctrl rows us-3..us (4 rows x 64 cols x 4 comps f32), one float4
    //     per thread, fully coalesced
    {
        const int l   = tid >> 6;          // row within the 4  (tid/64)
        const int col = tid & 63;          // column
        int row = us - DEG + l;
        row = row < 0 ? 0 : (row > M_ - 1 ? M_ - 1 : row);   // JAX clip semantics
        const float4 v = *(const float4*)&ctrl[((size_t)(b * M_ + row) * N_ + col) * 4];
        rows[l][col][0] = v.x; rows[l][col][1] = v.y;
        rows[l][col][2] = v.z; rows[l][col][3] = v.w;
    }
    __syncthreads();

    // --- accumulate surf[b,u,v,0:3]
    const int   vs = sspan[tid];
    const float NuA[4] = {Nu0, Nu1, Nu2, Nu3};
    const float NvA[4] = {sN[tid][0], sN[tid][1], sN[tid][2], sN[tid][3]};
    float a0 = 0.f, a1 = 0.f, a2 = 0.f;
    #pragma unroll
    for (int r = 0; r < 4; ++r) {
        int col = vs - DEG + r;
        col = col < 0 ? 0 : (col > N_ - 1 ? N_ - 1 : col);
        #pragma unroll
        for (int l = 0; l < 4; ++l) {
            const float w = NuA[l] * NvA[r];
            a0 += w * rows[l][col][0];
            a1 += w * rows[l][col][1];
            a2 += w * rows[l][col][2];
        }
    }

    const size_t o = ((size_t)blockIdx.x * T_ + tid) * 3;
    out[o + 0] = a0;
    out[o + 1] = a1;
    out[o + 2] = a2;
}

extern "C" void kernel_launch(void* const* d_in, const int* in_sizes, int n_in,
                              void* d_out, int out_size, void* d_ws, size_t ws_size,
                              hipStream_t stream) {
    const float* ctrl   = (const float*)d_in[0];
    const float* knot_u = (const float*)d_in[1];
    // d_in[2] (knot_v) is unused: reference builds V from knot_u.
    float* out = (float*)d_out;

    dim3 grid(B_ * T_);   // one block per (batch, u-sample)
    dim3 block(T_);       // one thread per v-sample
    surf_eval_kernel<<<grid, block, 0, stream>>>(ctrl, knot_u, out);
}

// Round 3
// 72.008 us; speedup vs baseline: 1.1518x; 1.1518x over previous
//
#include <hip/hip_runtime.h>
#include <hip/hip_bf16.h>

// Problem: B=16, M=N=64, P=Q=3, OUT_U=OUT_V=256, f32 in/out.
// Reference quirks kept faithful:
//  - V is built from knot_u (source bug) and u==v linspace, P==Q
//    => v-direction spans & basis are IDENTICAL to u-direction.
//  - Output keeps only comps 0..2 of the 4-comp ctrl points.
//  - np.cumsum is sequential; mirrored exactly (single-thread f32 chain).
//
// Structure (R3): two kernels.
//  A: 16 blocks — per-(batch,t) span + cubic basis once into d_ws (was
//     redundantly recomputed in all 4096 blocks before).
//  B: 4096 blocks (b,u) × 256 threads (v) — gather + 48 FMA + store.
constexpr int B_   = 16;
constexpr int M_   = 64;
constexpr int N_   = 64;
constexpr int DEG  = 3;
constexpr int T_   = 256;   // OUT_U == OUT_V
constexpr int KLEN = 68;    // M + P + 1

__global__ __launch_bounds__(256)
void basis_kernel(const float* __restrict__ knot_u,
                  float4* __restrict__ ws_basis,   // [B*T]
                  int*    __restrict__ ws_span) {  // [B*T]
    const int b   = blockIdx.x;
    const int tid = threadIdx.x;

    __shared__ float su[KLEN];

    // normalized cumsum (sequential, mirrors np.cumsum)
    if (tid == 0) {
        float acc = 0.f;
        for (int i = 0; i < KLEN; ++i) {
            acc += knot_u[b * KLEN + i];
            su[i] = acc;
        }
        const float c0 = su[0];
        const float d  = su[KLEN - 1] - c0;
        for (int i = 0; i < KLEN; ++i) su[i] = (su[i] - c0) / d;
    }
    __syncthreads();

    // t = linspace(1e-5, 1-1e-5, 256)[tid]
    const float tt = 1e-5f + (float)tid * ((1.0f - 2e-5f) / 255.0f);

    // span: first-occurrence argmin of (t - U[s+3]) where > 1e-8 else 1.0
    float best = 1e30f; int bs = 0;
    for (int s = 0; s < KLEN - 2 * DEG; ++s) {       // 62 candidates
        float dd   = tt - su[s + DEG];
        float cand = (dd > 1e-8f) ? dd : 1.0f;
        if (cand < best) { best = cand; bs = s; }    // strict < keeps first min
    }
    const int span = bs + DEG;

    // Cox-de Boor, degree 3, exact reference arithmetic order
    float Ni[4] = {1.f, 0.f, 0.f, 0.f};
    for (int k = 1; k <= DEG; ++k) {
        float saved = 0.f;
        for (int r = 0; r < k; ++r) {
            const float K1   = su[span + r + 1];
            const float K2   = su[span + 1 - k + r];
            const float temp = Ni[r] / ((K1 - tt) + (tt - K2));
            Ni[r] = saved + (K1 - tt) * temp;
            saved = (tt - K2) * temp;
        }
        Ni[k] = saved;
    }

    ws_basis[b * T_ + tid] = make_float4(Ni[0], Ni[1], Ni[2], Ni[3]);
    ws_span [b * T_ + tid] = span;
}

__global__ __launch_bounds__(256)
void eval_kernel(const float*  __restrict__ ctrl,
                 const float4* __restrict__ ws_basis,
                 const int*    __restrict__ ws_span,
                 float*        __restrict__ out) {
    const int b   = blockIdx.x >> 8;   // batch
    const int u   = blockIdx.x & 255;  // u-sample of this block
    const int tid = threadIdx.x;       // v-sample

    __shared__ float4 rows[4][N_];     // 4 staged ctrl rows (float4 per point)

    // per-thread v basis (coalesced, L2-hot) + uniform u basis (broadcast)
    const float4 Nv = ws_basis[b * T_ + tid];
    const int    vs = ws_span [b * T_ + tid];
    const float4 Nu = ws_basis[b * T_ + u];
    const int    us = ws_span [b * T_ + u];

    // stage ctrl rows us-3..us: one float4 per thread, fully coalesced
    {
        const int l   = tid >> 6;      // row within the 4
        const int col = tid & 63;      // column
        int row = us - DEG + l;
        row = row < 0 ? 0 : (row > M_ - 1 ? M_ - 1 : row);   // JAX clip
        rows[l][col] = *(const float4*)&ctrl[((size_t)(b * M_ + row) * N_ + col) * 4];
    }
    __syncthreads();

    const float NuA[4] = {Nu.x, Nu.y, Nu.z, Nu.w};
    const float NvA[4] = {Nv.x, Nv.y, Nv.z, Nv.w};
    float a0 = 0.f, a1 = 0.f, a2 = 0.f;
    #pragma unroll
    for (int r = 0; r < 4; ++r) {
        int col = vs - DEG + r;
        col = col < 0 ? 0 : (col > N_ - 1 ? N_ - 1 : col);   // JAX clip
        #pragma unroll
        for (int l = 0; l < 4; ++l) {
            const float  w  = NuA[l] * NvA[r];
            const float4 cp = rows[l][col];
            a0 += w * cp.x;
            a1 += w * cp.y;
            a2 += w * cp.z;
        }
    }

    const size_t o = ((size_t)blockIdx.x * T_ + tid) * 3;
    out[o + 0] = a0;
    out[o + 1] = a1;
    out[o + 2] = a2;
}

extern "C" void kernel_launch(void* const* d_in, const int* in_sizes, int n_in,
                              void* d_out, int out_size, void* d_ws, size_t ws_size,
                              hipStream_t stream) {
    const float* ctrl   = (const float*)d_in[0];
    const float* knot_u = (const float*)d_in[1];
    // d_in[2] (knot_v) unused: reference builds V from knot_u.
    float* out = (float*)d_out;

    // workspace layout: [0,64KB) float4 basis[B*T], [64KB,80KB) int span[B*T]
    float4* ws_basis = (float4*)d_ws;
    int*    ws_span  = (int*)((char*)d_ws + (size_t)B_ * T_ * sizeof(float4));

    basis_kernel<<<dim3(B_), dim3(T_), 0, stream>>>(knot_u, ws_basis, ws_span);
    eval_kernel <<<dim3(B_ * T_), dim3(T_), 0, stream>>>(ctrl, ws_basis, ws_span, out);
}

// Round 4
// 70.185 us; speedup vs baseline: 1.1817x; 1.0260x over previous
//
#include <hip/hip_runtime.h>
#include <hip/hip_bf16.h>

// Problem: B=16, M=N=64, P=Q=3, OUT_U=OUT_V=256, f32 in/out.
// Reference quirks kept faithful:
//  - V is built from knot_u (source bug) and u==v linspace, P==Q
//    => v-direction spans & basis are IDENTICAL to u-direction.
//  - Output keeps only comps 0..2 of the 4-comp ctrl points.
//  - np.cumsum is sequential; mirrored exactly (single-thread f32 chain).
//
// R4 structure:
//  A: 16 blocks — per-(batch,t) span + cubic basis into d_ws (computed once).
//  B: 4096 blocks (b,u) × 256 threads (v):
//     phase 1: 192 threads build rowU[col][c] = sum_l Nu[l]*ctrl[row_l][col][c]
//              directly from global (ctrl is L2-hot: 256 KB/batch × 256 reuses)
//     phase 2: per thread 4x ds_read_b128 + 12 FMA + 3 stores.
//     (was: per-thread float4 stage + ds_write + 16x ds_read_b128 + 48 FMA)
constexpr int B_   = 16;
constexpr int M_   = 64;
constexpr int N_   = 64;
constexpr int DEG  = 3;
constexpr int T_   = 256;   // OUT_U == OUT_V
constexpr int KLEN = 68;    // M + P + 1

__global__ __launch_bounds__(256)
void basis_kernel(const float* __restrict__ knot_u,
                  float4* __restrict__ ws_basis,   // [B*T]
                  int*    __restrict__ ws_span) {  // [B*T]
    const int b   = blockIdx.x;
    const int tid = threadIdx.x;

    __shared__ float su[KLEN];

    // normalized cumsum (sequential, mirrors np.cumsum)
    if (tid == 0) {
        float acc = 0.f;
        for (int i = 0; i < KLEN; ++i) {
            acc += knot_u[b * KLEN + i];
            su[i] = acc;
        }
        const float c0 = su[0];
        const float d  = su[KLEN - 1] - c0;
        for (int i = 0; i < KLEN; ++i) su[i] = (su[i] - c0) / d;
    }
    __syncthreads();

    // t = linspace(1e-5, 1-1e-5, 256)[tid]
    const float tt = 1e-5f + (float)tid * ((1.0f - 2e-5f) / 255.0f);

    // span: first-occurrence argmin of (t - U[s+3]) where > 1e-8 else 1.0
    float best = 1e30f; int bs = 0;
    for (int s = 0; s < KLEN - 2 * DEG; ++s) {       // 62 candidates
        float dd   = tt - su[s + DEG];
        float cand = (dd > 1e-8f) ? dd : 1.0f;
        if (cand < best) { best = cand; bs = s; }    // strict < keeps first min
    }
    const int span = bs + DEG;

    // Cox-de Boor, degree 3, exact reference arithmetic order
    float Ni[4] = {1.f, 0.f, 0.f, 0.f};
    for (int k = 1; k <= DEG; ++k) {
        float saved = 0.f;
        for (int r = 0; r < k; ++r) {
            const float K1   = su[span + r + 1];
            const float K2   = su[span + 1 - k + r];
            const float temp = Ni[r] / ((K1 - tt) + (tt - K2));
            Ni[r] = saved + (K1 - tt) * temp;
            saved = (tt - K2) * temp;
        }
        Ni[k] = saved;
    }

    ws_basis[b * T_ + tid] = make_float4(Ni[0], Ni[1], Ni[2], Ni[3]);
    ws_span [b * T_ + tid] = span;
}

__global__ __launch_bounds__(256)
void eval_kernel(const float*  __restrict__ ctrl,
                 const float4* __restrict__ ws_basis,
                 const int*    __restrict__ ws_span,
                 float*        __restrict__ out) {
    const int b   = blockIdx.x >> 8;   // batch
    const int u   = blockIdx.x & 255;  // u-sample of this block
    const int tid = threadIdx.x;       // v-sample

    // rowU[col] = {c0,c1,c2,pad}: u-contracted control row (block-uniform u)
    __shared__ float4 rowU[N_];

    // per-thread v basis (coalesced, L2-hot) + uniform u basis (broadcast)
    const float4 Nv = ws_basis[b * T_ + tid];
    const int    vs = ws_span [b * T_ + tid];
    const float4 Nu = ws_basis[b * T_ + u];
    const int    us = ws_span [b * T_ + u];

    // phase 1: build rowU — 192 threads, one (col, comp) each, straight from L2
    if (tid < 3 * N_) {
        const int col = tid / 3;       // 0..63
        const int c   = tid - col * 3; // 0..2
        float acc = 0.f;
        const float NuA[4] = {Nu.x, Nu.y, Nu.z, Nu.w};
        #pragma unroll
        for (int l = 0; l < 4; ++l) {
            int row = us - DEG + l;
            row = row < 0 ? 0 : (row > M_ - 1 ? M_ - 1 : row);   // JAX clip
            acc += NuA[l] * ctrl[((size_t)(b * M_ + row) * N_ + col) * 4 + c];
        }
        ((float*)&rowU[col])[c] = acc;
    }
    __syncthreads();

    // phase 2: v-contraction — 4x ds_read_b128 + 12 FMA
    const float NvA[4] = {Nv.x, Nv.y, Nv.z, Nv.w};
    float a0 = 0.f, a1 = 0.f, a2 = 0.f;
    #pragma unroll
    for (int r = 0; r < 4; ++r) {
        int col = vs - DEG + r;
        col = col < 0 ? 0 : (col > N_ - 1 ? N_ - 1 : col);       // JAX clip
        const float4 cp = rowU[col];
        a0 += NvA[r] * cp.x;
        a1 += NvA[r] * cp.y;
        a2 += NvA[r] * cp.z;
    }

    const size_t o = ((size_t)blockIdx.x * T_ + tid) * 3;
    out[o + 0] = a0;
    out[o + 1] = a1;
    out[o + 2] = a2;
}

extern "C" void kernel_launch(void* const* d_in, const int* in_sizes, int n_in,
                              void* d_out, int out_size, void* d_ws, size_t ws_size,
                              hipStream_t stream) {
    const float* ctrl   = (const float*)d_in[0];
    const float* knot_u = (const float*)d_in[1];
    // d_in[2] (knot_v) unused: reference builds V from knot_u.
    float* out = (float*)d_out;

    // workspace layout: [0,64KB) float4 basis[B*T], [64KB,80KB) int span[B*T]
    float4* ws_basis = (float4*)d_ws;
    int*    ws_span  = (int*)((char*)d_ws + (size_t)B_ * T_ * sizeof(float4));

    basis_kernel<<<dim3(B_), dim3(T_), 0, stream>>>(knot_u, ws_basis, ws_span);
    eval_kernel <<<dim3(B_ * T_), dim3(T_), 0, stream>>>(ctrl, ws_basis, ws_span, out);
}

// Round 5
// 69.888 us; speedup vs baseline: 1.1867x; 1.0042x over previous
//
#include <hip/hip_runtime.h>
#include <hip/hip_bf16.h>

// Problem: B=16, M=N=64, P=Q=3, OUT_U=OUT_V=256, f32 in/out.
// Reference quirks kept faithful:
//  - V is built from knot_u (source bug) and u==v linspace, P==Q
//    => v-direction spans & basis are IDENTICAL to u-direction.
//  - Output keeps only comps 0..2 of the 4-comp ctrl points.
//  - np.cumsum is sequential; mirrored exactly (single-thread f32 chain).
//
// R5 structure:
//  A: 16 blocks — per-(batch,t) span + cubic basis into d_ws (once).
//  B: 2048 blocks, each handles TWO consecutive u's (halves v-basis L2
//     traffic + dispatch count; output region per block is 6 KB contiguous):
//     phase 1: 192 threads build rowU[j][col] = sum_l Nu[l]*ctrl[row_l][col]
//     phase 2: per thread 2 points: 8x LDS float4 read + 24 FMA -> LDS obuf
//     phase 3: coalesced float4 stores of the 6 KB block output.
constexpr int B_   = 16;
constexpr int M_   = 64;
constexpr int N_   = 64;
constexpr int DEG  = 3;
constexpr int T_   = 256;   // OUT_U == OUT_V
constexpr int KLEN = 68;    // M + P + 1

__global__ __launch_bounds__(256)
void basis_kernel(const float* __restrict__ knot_u,
                  float4* __restrict__ ws_basis,   // [B*T]
                  int*    __restrict__ ws_span) {  // [B*T]
    const int b   = blockIdx.x;
    const int tid = threadIdx.x;

    __shared__ float su[KLEN];

    // normalized cumsum (sequential, mirrors np.cumsum)
    if (tid == 0) {
        float acc = 0.f;
        for (int i = 0; i < KLEN; ++i) {
            acc += knot_u[b * KLEN + i];
            su[i] = acc;
        }
        const float c0 = su[0];
        const float d  = su[KLEN - 1] - c0;
        for (int i = 0; i < KLEN; ++i) su[i] = (su[i] - c0) / d;
    }
    __syncthreads();

    // t = linspace(1e-5, 1-1e-5, 256)[tid]
    const float tt = 1e-5f + (float)tid * ((1.0f - 2e-5f) / 255.0f);

    // span: first-occurrence argmin of (t - U[s+3]) where > 1e-8 else 1.0
    float best = 1e30f; int bs = 0;
    for (int s = 0; s < KLEN - 2 * DEG; ++s) {       // 62 candidates
        float dd   = tt - su[s + DEG];
        float cand = (dd > 1e-8f) ? dd : 1.0f;
        if (cand < best) { best = cand; bs = s; }    // strict < keeps first min
    }
    const int span = bs + DEG;

    // Cox-de Boor, degree 3, exact reference arithmetic order
    float Ni[4] = {1.f, 0.f, 0.f, 0.f};
    for (int k = 1; k <= DEG; ++k) {
        float saved = 0.f;
        for (int r = 0; r < k; ++r) {
            const float K1   = su[span + r + 1];
            const float K2   = su[span + 1 - k + r];
            const float temp = Ni[r] / ((K1 - tt) + (tt - K2));
            Ni[r] = saved + (K1 - tt) * temp;
            saved = (tt - K2) * temp;
        }
        Ni[k] = saved;
    }

    ws_basis[b * T_ + tid] = make_float4(Ni[0], Ni[1], Ni[2], Ni[3]);
    ws_span [b * T_ + tid] = span;
}

__global__ __launch_bounds__(256)
void eval_kernel(const float*  __restrict__ ctrl,
                 const float4* __restrict__ ws_basis,
                 const int*    __restrict__ ws_span,
                 float*        __restrict__ out) {
    const int b   = blockIdx.x >> 7;          // 2048 blocks: 16 b × 128 u-pairs
    const int u0  = (blockIdx.x & 127) * 2;   // first of two u's
    const int tid = threadIdx.x;              // v-sample

    __shared__ float4 rowU[2][N_];            // u-contracted ctrl rows (2 u's)
    __shared__ __align__(16) float obuf[2 * T_ * 3];  // 6 KB output staging

    // per-thread v basis (coalesced, L2-hot)
    const float4 Nv = ws_basis[b * T_ + tid];
    const int    vs = ws_span [b * T_ + tid];

    // phase 1: rowU[j][col][c] = sum_l Nu[l]*ctrl[row_l][col][c]
    // (u-basis lookups are block-uniform -> scalar loads)
    if (tid < 3 * N_) {
        const int col = tid / 3;       // 0..63
        const int c   = tid - col * 3; // 0..2
        #pragma unroll
        for (int j = 0; j < 2; ++j) {
            const int    uu = u0 + j;
            const float4 Nu = ws_basis[b * T_ + uu];
            const int    us = ws_span [b * T_ + uu];
            const float NuA[4] = {Nu.x, Nu.y, Nu.z, Nu.w};
            float acc = 0.f;
            #pragma unroll
            for (int l = 0; l < 4; ++l) {
                int row = us - DEG + l;
                row = row < 0 ? 0 : (row > M_ - 1 ? M_ - 1 : row);   // JAX clip
                acc += NuA[l] * ctrl[((size_t)(b * M_ + row) * N_ + col) * 4 + c];
            }
            ((float*)&rowU[j][col])[c] = acc;
        }
    }
    __syncthreads();

    // phase 2: v-contraction for both u's -> LDS staging
    const float NvA[4] = {Nv.x, Nv.y, Nv.z, Nv.w};
    #pragma unroll
    for (int j = 0; j < 2; ++j) {
        float a0 = 0.f, a1 = 0.f, a2 = 0.f;
        #pragma unroll
        for (int r = 0; r < 4; ++r) {
            int col = vs - DEG + r;
            col = col < 0 ? 0 : (col > N_ - 1 ? N_ - 1 : col);       // JAX clip
            const float4 cp = rowU[j][col];
            a0 += NvA[r] * cp.x;
            a1 += NvA[r] * cp.y;
            a2 += NvA[r] * cp.z;
        }
        // stride-3 dword writes: 3 is coprime with 32 banks -> conflict-free
        obuf[(j * T_ + tid) * 3 + 0] = a0;
        obuf[(j * T_ + tid) * 3 + 1] = a1;
        obuf[(j * T_ + tid) * 3 + 2] = a2;
    }
    __syncthreads();

    // phase 3: coalesced float4 stores (1536 floats = 384 float4)
    float4*       dst = (float4*)(out + (size_t)(b * T_ + u0) * T_ * 3);
    const float4* src = (const float4*)obuf;
    dst[tid] = src[tid];
    if (tid < 128) dst[T_ + tid] = src[T_ + tid];
}

extern "C" void kernel_launch(void* const* d_in, const int* in_sizes, int n_in,
                              void* d_out, int out_size, void* d_ws, size_t ws_size,
                              hipStream_t stream) {
    const float* ctrl   = (const float*)d_in[0];
    const float* knot_u = (const float*)d_in[1];
    // d_in[2] (knot_v) unused: reference builds V from knot_u.
    float* out = (float*)d_out;

    // workspace layout: [0,64KB) float4 basis[B*T], [64KB,80KB) int span[B*T]
    float4* ws_basis = (float4*)d_ws;
    int*    ws_span  = (int*)((char*)d_ws + (size_t)B_ * T_ * sizeof(float4));

    basis_kernel<<<dim3(B_), dim3(T_), 0, stream>>>(knot_u, ws_basis, ws_span);
    eval_kernel <<<dim3(B_ * T_ / 2), dim3(T_), 0, stream>>>(ctrl, ws_basis, ws_span, out);
}